// Round 3
// baseline (1427.528 us; speedup 1.0000x reference)
//
#include <hip/hip_runtime.h>
#include <hip/hip_bf16.h>

#define N_NODES 100000
#define E_EDGES 1600000
#define T_TGT   4096
#define P_PAIRS 131072
#define NCHUNK  98   // ceil(N_NODES/1024)

typedef __bf16 bf16x8 __attribute__((ext_vector_type(8)));
typedef float  f32x4  __attribute__((ext_vector_type(4)));

__device__ __forceinline__ float b2f(unsigned short u) {
  unsigned int x = ((unsigned int)u) << 16;
  return __builtin_bit_cast(float, x);
}
__device__ __forceinline__ unsigned short f2b(float f) {
  unsigned int x = __builtin_bit_cast(unsigned int, f);
  x += 0x7fffu + ((x >> 16) & 1u);
  return (unsigned short)(x >> 16);
}
__device__ __forceinline__ bf16x8 ld8(const unsigned short* p) {
  return *reinterpret_cast<const bf16x8*>(p);
}
__device__ __forceinline__ f32x4 mfma16(bf16x8 a, bf16x8 b, f32x4 c) {
  return __builtin_amdgcn_mfma_f32_16x16x32_bf16(a, b, c, 0, 0, 0);
}
// dual-dtype scalar read: element i of a float tensor that is fp32 or bf16
__device__ __forceinline__ float ldf(const void* p, size_t i, bool f32) {
  return f32 ? ((const float*)p)[i] : b2f(((const unsigned short*)p)[i]);
}
// dual-dtype 8-element A/B fragment load (elem = element offset, 8 contiguous)
__device__ __forceinline__ bf16x8 ld8d(const void* p, size_t elem, bool f32) {
  if (!f32) return ld8((const unsigned short*)p + elem);
  const float* q = (const float*)p + elem;
  union { bf16x8 v; unsigned short s[8]; } u;
#pragma unroll
  for (int j = 0; j < 8; ++j) u.s[j] = f2b(q[j]);
  return u.v;
}

// ---------------- dtype sniff ----------------
// fp32 storage: low-short exponent field of each 32b word is ~uniform ->
// mostly outside [90,140]. bf16 storage: low short is a real ~N(0,1) bf16 ->
// exponent in [90,140] essentially always. Vote over 256 sampled words.
__global__ void k_sniff(const unsigned int* __restrict__ x, int* __restrict__ dflag) {
  unsigned int w = x[(size_t)threadIdx.x * 24001];  // < 6.4M words (bf16 lower bound)
  int e = (w >> 7) & 0xff;
  if (e < 90 || e > 140) atomicAdd(dflag, 1);
}

// ---------------- graph prep ----------------
__global__ void k_hist(const int* __restrict__ dst, int* __restrict__ cnt) {
  for (int e = blockIdx.x * blockDim.x + threadIdx.x; e < E_EDGES;
       e += gridDim.x * blockDim.x)
    atomicAdd(&cnt[dst[e]], 1);
}

__global__ void k_deginv(const int* __restrict__ cnt, float* __restrict__ dinv) {
  int n = blockIdx.x * blockDim.x + threadIdx.x;
  if (n < N_NODES) dinv[n] = 1.0f / (float)max(cnt[n], 1);
}

__global__ void k_scan_a(const int* __restrict__ cnt, int* __restrict__ part) {
  __shared__ int sd[256];
  int t = threadIdx.x;
  int base = blockIdx.x * 1024 + t * 4;
  int s = 0;
  for (int j = 0; j < 4; ++j) {
    int idx = base + j;
    if (idx < N_NODES) s += cnt[idx];
  }
  sd[t] = s; __syncthreads();
  for (int off = 128; off > 0; off >>= 1) {
    if (t < off) sd[t] += sd[t + off];
    __syncthreads();
  }
  if (t == 0) part[blockIdx.x] = sd[0];
}

__global__ void k_scan_b(int* __restrict__ part, int* __restrict__ offs) {
  int run = 0;
  for (int i = 0; i < NCHUNK; ++i) { int v = part[i]; part[i] = run; run += v; }
  offs[N_NODES] = run;
}

__global__ void k_scan_c(const int* __restrict__ cnt, const int* __restrict__ part,
                         int* __restrict__ offs) {
  __shared__ int sd[256];
  int t = threadIdx.x;
  int base = blockIdx.x * 1024 + t * 4;
  int v[4]; int s = 0;
  for (int j = 0; j < 4; ++j) {
    int idx = base + j;
    v[j] = (idx < N_NODES) ? cnt[idx] : 0;
    s += v[j];
  }
  sd[t] = s; __syncthreads();
  for (int off = 1; off < 256; off <<= 1) {
    int x = (t >= off) ? sd[t - off] : 0;
    __syncthreads();
    sd[t] += x;
    __syncthreads();
  }
  int excl = sd[t] - s + part[blockIdx.x];
  for (int j = 0; j < 4; ++j) {
    int idx = base + j;
    if (idx < N_NODES) { offs[idx] = excl; excl += v[j]; }
  }
}

__global__ void k_fill(const int* __restrict__ src, const int* __restrict__ dst,
                       const int* __restrict__ offs, int* __restrict__ cur,
                       int* __restrict__ csr) {
  for (int e = blockIdx.x * blockDim.x + threadIdx.x; e < E_EDGES;
       e += gridDim.x * blockDim.x) {
    int d = dst[e];
    int p = offs[d] + atomicAdd(&cur[d], 1);
    csr[p] = src[e];
  }
}

// ---------------- small utils (dual-dtype reads) ----------------
__global__ void k_transpose(const void* __restrict__ in,
                            unsigned short* __restrict__ out, int K, int Nc,
                            int Kpad, int total, const int* __restrict__ dflag) {
  bool f32 = *dflag > 128;
  int i = blockIdx.x * blockDim.x + threadIdx.x;
  if (i >= total) return;
  int n = i / Kpad, k = i % Kpad;
  out[i] = (k < K) ? f2b(ldf(in, (size_t)k * Nc + n, f32)) : (unsigned short)0;
}

__global__ void k_pe(const void* __restrict__ pos, const void* __restrict__ wpe,
                     unsigned short* __restrict__ pe, const int* __restrict__ dflag) {
  bool f32 = *dflag > 128;
  int n = blockIdx.x * blockDim.x + threadIdx.x;
  if (n >= N_NODES) return;
  float p[4];
  for (int j = 0; j < 4; ++j) p[j] = ldf(pos, (size_t)n * 4 + j, f32);
  for (int i = 0; i < 4; ++i) {
    float acc = 0.f;
    for (int j = 0; j < 4; ++j) acc += p[j] * ldf(wpe, i * 4 + j, f32);  // pos @ Wpe.T
    pe[(size_t)n * 4 + i] = f2b(acc);
  }
}

// ---------------- aggregation (CSR gather, bf16 in/out) ----------------
__global__ void k_agg(const unsigned short* __restrict__ in,
                      const int* __restrict__ offs, const int* __restrict__ csr,
                      const float* __restrict__ dinv,
                      unsigned short* __restrict__ out, int nrows,
                      const int* __restrict__ map, int relu) {
  const int lane = threadIdx.x & 63;
  int gw = (blockIdx.x * blockDim.x + threadIdx.x) >> 6;
  int nw = (gridDim.x * blockDim.x) >> 6;
  for (int i = gw; i < nrows; i += nw) {
    int n = map ? map[i] : i;
    int b = offs[n], e = offs[n + 1];
    float a0 = 0.f, a1 = 0.f;
    for (int j = b; j < e; ++j) {
      int s = csr[j];
      unsigned int v =
          *reinterpret_cast<const unsigned int*>(in + (size_t)s * 128 + lane * 2);
      a0 += b2f((unsigned short)(v & 0xffffu));
      a1 += b2f((unsigned short)(v >> 16));
    }
    float sc = dinv[n];
    a0 *= sc; a1 *= sc;
    if (relu) { a0 = fmaxf(a0, 0.f); a1 = fmaxf(a1, 0.f); }
    unsigned int o = (unsigned int)f2b(a0) | ((unsigned int)f2b(a1) << 16);
    *reinterpret_cast<unsigned int*>(out + (size_t)i * 128 + lane * 2) = o;
  }
}

// ---------------- GEMMs (bf16 MFMA 16x16x32) ----------------
// layer-1 GEMM: A raw (fp32 or bf16) -> C bf16.   C = A * B, BT = B^T.
template <int NT, int KS>
__global__ void __launch_bounds__(256) k_gemm_in(const void* __restrict__ A,
                                                 const unsigned short* __restrict__ BT,
                                                 unsigned short* __restrict__ C, int M,
                                                 int ldb,
                                                 const int* __restrict__ dflag) {
  bool f32 = *dflag > 128;
  const int wid = threadIdx.x >> 6;
  const int lane = threadIdx.x & 63;
  const int lr = lane & 15;
  const int q = lane >> 4;
  const int m0 = blockIdx.x * 64 + wid * 16;
  if (m0 >= M) return;
  f32x4 acc[NT];
#pragma unroll
  for (int i = 0; i < NT; ++i) acc[i] = f32x4{0.f, 0.f, 0.f, 0.f};
  const size_t abase = (size_t)(m0 + lr) * (KS * 32) + q * 8;
#pragma unroll
  for (int ks = 0; ks < KS; ++ks) {
    bf16x8 a = ld8d(A, abase + ks * 32, f32);
#pragma unroll
    for (int nt = 0; nt < NT; ++nt) {
      bf16x8 b = ld8(BT + (size_t)(nt * 16 + lr) * ldb + ks * 32 + q * 8);
      acc[nt] = mfma16(a, b, acc[nt]);
    }
  }
#pragma unroll
  for (int nt = 0; nt < NT; ++nt)
#pragma unroll
    for (int r = 0; r < 4; ++r)
      C[(size_t)(m0 + q * 4 + r) * (NT * 16) + nt * 16 + lr] = f2b(acc[nt][r]);
}

// pure-bf16 GEMM (safe in-place C==A: wave reads only its own 16-row slab)
template <int NT, int KS>
__global__ void __launch_bounds__(256) k_gemm(const unsigned short* __restrict__ A,
                                              const unsigned short* __restrict__ BT,
                                              unsigned short* __restrict__ C, int M,
                                              int ldb) {
  const int wid = threadIdx.x >> 6;
  const int lane = threadIdx.x & 63;
  const int lr = lane & 15;
  const int q = lane >> 4;
  const int m0 = blockIdx.x * 64 + wid * 16;
  if (m0 >= M) return;
  f32x4 acc[NT];
#pragma unroll
  for (int i = 0; i < NT; ++i) acc[i] = f32x4{0.f, 0.f, 0.f, 0.f};
  const unsigned short* arow = A + (size_t)(m0 + lr) * (KS * 32) + q * 8;
#pragma unroll
  for (int ks = 0; ks < KS; ++ks) {
    bf16x8 a = ld8(arow + ks * 32);
#pragma unroll
    for (int nt = 0; nt < NT; ++nt) {
      bf16x8 b = ld8(BT + (size_t)(nt * 16 + lr) * ldb + ks * 32 + q * 8);
      acc[nt] = mfma16(a, b, acc[nt]);
    }
  }
#pragma unroll
  for (int nt = 0; nt < NT; ++nt)
#pragma unroll
    for (int r = 0; r < 4; ++r)
      C[(size_t)(m0 + q * 4 + r) * (NT * 16) + nt * 16 + lr] = f2b(acc[nt][r]);
}

// target-embedding GEMM: bf16 A -> dual-dtype store into d_out at elem_off
template <int NT, int KS>
__global__ void __launch_bounds__(256) k_gemm_out(const unsigned short* __restrict__ A,
                                                  const unsigned short* __restrict__ BT,
                                                  void* __restrict__ C, size_t elem_off,
                                                  int M, int ldb,
                                                  const int* __restrict__ dflag) {
  bool f32 = *dflag > 128;
  const int wid = threadIdx.x >> 6;
  const int lane = threadIdx.x & 63;
  const int lr = lane & 15;
  const int q = lane >> 4;
  const int m0 = blockIdx.x * 64 + wid * 16;
  if (m0 >= M) return;
  f32x4 acc[NT];
#pragma unroll
  for (int i = 0; i < NT; ++i) acc[i] = f32x4{0.f, 0.f, 0.f, 0.f};
  const unsigned short* arow = A + (size_t)(m0 + lr) * (KS * 32) + q * 8;
#pragma unroll
  for (int ks = 0; ks < KS; ++ks) {
    bf16x8 a = ld8(arow + ks * 32);
#pragma unroll
    for (int nt = 0; nt < NT; ++nt) {
      bf16x8 b = ld8(BT + (size_t)(nt * 16 + lr) * ldb + ks * 32 + q * 8);
      acc[nt] = mfma16(a, b, acc[nt]);
    }
  }
#pragma unroll
  for (int nt = 0; nt < NT; ++nt)
#pragma unroll
    for (int r = 0; r < 4; ++r) {
      size_t idx = elem_off + (size_t)(m0 + q * 4 + r) * (NT * 16) + nt * 16 + lr;
      if (f32) ((float*)C)[idx] = acc[nt][r];
      else     ((unsigned short*)C)[idx] = f2b(acc[nt][r]);
    }
}

// ---------------- fused predictor ----------------
// out = (relu(feat@Wp1+b1)@Wp2+b2)*mask; feat built on the fly (K 200->224).
// Hidden tile in LDS. z/b1/b2/pmask raw (dual-dtype); out store dual-dtype.
__global__ void __launch_bounds__(256) k_pred(
    const unsigned short* __restrict__ ctx, const void* __restrict__ z,
    const unsigned short* __restrict__ pe, const int* __restrict__ pair_s,
    const int* __restrict__ pair_t, const int* __restrict__ tn,
    const unsigned short* __restrict__ w1T, const void* __restrict__ b1,
    const unsigned short* __restrict__ w2T, const void* __restrict__ b2,
    const void* __restrict__ pmask, void* __restrict__ out,
    const int* __restrict__ dflag) {
  bool f32 = *dflag > 128;
  __shared__ unsigned short sh[4][16][264];  // +8 pad breaks bank clash
  const int wid = threadIdx.x >> 6;
  const int lane = threadIdx.x & 63;
  const int lr = lane & 15;
  const int q = lane >> 4;
  const int m0 = blockIdx.x * 64 + wid * 16;
  const int row = m0 + lr;
  const int s = pair_s[row];
  const int tno = tn[pair_t[row]];
  const unsigned short* ctxrow = ctx + (size_t)s * 128 + q * 8;

  // ---- layer 1 ----
  f32x4 acc[16];
#pragma unroll
  for (int i = 0; i < 16; ++i) acc[i] = f32x4{0.f, 0.f, 0.f, 0.f};
#pragma unroll
  for (int ks = 0; ks < 7; ++ks) {
    const int kb = ks * 32 + q * 8;
    bf16x8 a;
    if (kb < 128) {
      a = ld8(ctxrow + ks * 32);
    } else if (kb < 192) {
      a = ld8d(z, kb - 128, f32);
    } else if (kb == 192) {
      union { bf16x8 v; unsigned long long d[2]; } u;
      u.d[0] = *reinterpret_cast<const unsigned long long*>(pe + (size_t)s * 4);
      u.d[1] = *reinterpret_cast<const unsigned long long*>(pe + (size_t)tno * 4);
      a = u.v;
    } else {
      union { bf16x8 v; unsigned long long d[2]; } u;
      u.d[0] = 0; u.d[1] = 0;
      a = u.v;
    }
#pragma unroll
    for (int nt = 0; nt < 16; ++nt) {
      bf16x8 b = ld8(w1T + (size_t)(nt * 16 + lr) * 224 + kb);
      acc[nt] = mfma16(a, b, acc[nt]);
    }
  }
#pragma unroll
  for (int nt = 0; nt < 16; ++nt) {
    float bias = ldf(b1, nt * 16 + lr, f32);
#pragma unroll
    for (int r = 0; r < 4; ++r)
      sh[wid][q * 4 + r][nt * 16 + lr] = f2b(fmaxf(acc[nt][r] + bias, 0.f));
  }
  __syncthreads();

  // ---- layer 2 ----
  f32x4 acc2[8];
#pragma unroll
  for (int i = 0; i < 8; ++i) acc2[i] = f32x4{0.f, 0.f, 0.f, 0.f};
  const unsigned short* hrow = &sh[wid][lr][q * 8];
#pragma unroll
  for (int ks = 0; ks < 8; ++ks) {
    bf16x8 a = ld8(hrow + ks * 32);
#pragma unroll
    for (int nt = 0; nt < 8; ++nt) {
      bf16x8 b = ld8(w2T + (size_t)(nt * 16 + lr) * 256 + ks * 32 + q * 8);
      acc2[nt] = mfma16(a, b, acc2[nt]);
    }
  }
#pragma unroll
  for (int nt = 0; nt < 8; ++nt) {
    float bias = ldf(b2, nt * 16 + lr, f32);
#pragma unroll
    for (int r = 0; r < 4; ++r) {
      int rr = m0 + q * 4 + r;
      float mk = ldf(pmask, rr, f32);
      float v = (acc2[nt][r] + bias) * mk;
      size_t idx = (size_t)rr * 128 + nt * 16 + lr;
      if (f32) ((float*)out)[idx] = v;
      else     ((unsigned short*)out)[idx] = f2b(v);
    }
  }
}

extern "C" void kernel_launch(void* const* d_in, const int* in_sizes, int n_in,
                              void* d_out, int out_size, void* d_ws, size_t ws_size,
                              hipStream_t stream) {
  const void* x    = d_in[0];
  const void* mx   = d_in[1];
  const void* pos  = d_in[2];
  const int* esrc  = (const int*)d_in[3];
  const int* edst  = (const int*)d_in[4];
  const int* tn    = (const int*)d_in[5];
  const int* pt    = (const int*)d_in[6];
  const int* ps    = (const int*)d_in[7];
  const void* pmask= d_in[8];
  const void* W1t  = d_in[9];
  const void* W2t  = d_in[10];
  const void* W1c  = d_in[11];
  const void* W2c  = d_in[12];
  const void* Wpe  = d_in[13];
  const void* z    = d_in[14];
  const void* Wp1  = d_in[15];
  const void* bp1  = d_in[16];
  const void* Wp2  = d_in[17];
  const void* bp2  = d_in[18];

  char* w = (char*)d_ws;
  auto carve = [&](size_t bytes) -> void* {
    void* p = (void*)w;
    w += (bytes + 255) & ~(size_t)255;
    return p;
  };
  int*   dflag = (int*)carve(256);
  int*   offs  = (int*)carve((N_NODES + 1) * sizeof(int));
  int*   cur   = (int*)carve(N_NODES * sizeof(int));
  int*   part  = (int*)carve(4096);
  int*   csr   = (int*)carve(E_EDGES * sizeof(int));
  float* dinv  = (float*)carve(N_NODES * sizeof(float));
  unsigned short* bufA  = (unsigned short*)carve((size_t)N_NODES * 128 * 2);
  unsigned short* peB   = (unsigned short*)carve((size_t)N_NODES * 4 * 2);
  unsigned short* gt    = (unsigned short*)carve((size_t)T_TGT * 128 * 2);
  unsigned short* w1tT  = (unsigned short*)carve(128 * 128 * 2);
  unsigned short* w2tT  = (unsigned short*)carve(128 * 128 * 2);
  unsigned short* w1cT  = (unsigned short*)carve(128 * 128 * 2);
  unsigned short* w2cT  = (unsigned short*)carve(128 * 128 * 2);
  unsigned short* wp1T  = (unsigned short*)carve(256 * 224 * 2);
  unsigned short* wp2T  = (unsigned short*)carve(128 * 256 * 2);
  // bufB overlays d_out's pred region (always >= 25.6MB in both dtypes; pred
  // rows are written last, so earlier uses are dead by then).
  unsigned short* bufB = (unsigned short*)d_out;

  // ---- dtype sniff ----
  hipMemsetAsync(dflag, 0, sizeof(int), stream);
  k_sniff<<<1, 256, 0, stream>>>((const unsigned int*)x, dflag);

  // ---- graph prep (CSR by dst + degrees) ----
  hipMemsetAsync(cur, 0, N_NODES * sizeof(int), stream);
  k_hist<<<1024, 256, 0, stream>>>(edst, cur);
  k_deginv<<<(N_NODES + 255) / 256, 256, 0, stream>>>(cur, dinv);
  k_scan_a<<<NCHUNK, 256, 0, stream>>>(cur, part);
  k_scan_b<<<1, 1, 0, stream>>>(part, offs);
  k_scan_c<<<NCHUNK, 256, 0, stream>>>(cur, part, offs);
  hipMemsetAsync(cur, 0, N_NODES * sizeof(int), stream);
  k_fill<<<1024, 256, 0, stream>>>(esrc, edst, offs, cur, csr);

  // ---- weight transposes (B^T layouts, dual-dtype reads) ----
  k_transpose<<<64, 256, 0, stream>>>(W1t, w1tT, 128, 128, 128, 128 * 128, dflag);
  k_transpose<<<64, 256, 0, stream>>>(W2t, w2tT, 128, 128, 128, 128 * 128, dflag);
  k_transpose<<<64, 256, 0, stream>>>(W1c, w1cT, 128, 128, 128, 128 * 128, dflag);
  k_transpose<<<64, 256, 0, stream>>>(W2c, w2cT, 128, 128, 128, 128 * 128, dflag);
  k_transpose<<<(256 * 224 + 255) / 256, 256, 0, stream>>>(Wp1, wp1T, 200, 256, 224,
                                                           256 * 224, dflag);
  k_transpose<<<128, 256, 0, stream>>>(Wp2, wp2T, 256, 128, 256, 128 * 256, dflag);

  k_pe<<<(N_NODES + 255) / 256, 256, 0, stream>>>(pos, Wpe, peB, dflag);

  const int gemmN_grid = (N_NODES + 63) / 64;  // 1563

  // ---- target GCN: emb = (agg(relu(agg(x@W1t)))[targets]) @ W2t ----
  k_gemm_in<8, 4><<<gemmN_grid, 256, 0, stream>>>(x, w1tT, bufA, N_NODES, 128, dflag);
  k_agg<<<1024, 256, 0, stream>>>(bufA, offs, csr, dinv, bufB, N_NODES, nullptr, 1);
  k_agg<<<256, 256, 0, stream>>>(bufB, offs, csr, dinv, gt, T_TGT, tn, 0);
  k_gemm_out<8, 4><<<T_TGT / 64, 256, 0, stream>>>(gt, w2tT, d_out,
                                                   (size_t)P_PAIRS * 128, T_TGT, 128,
                                                   dflag);

  // ---- context GCN: ctx = agg(relu(agg(mx@W1c))) @ W2c ----
  k_gemm_in<8, 4><<<gemmN_grid, 256, 0, stream>>>(mx, w1cT, bufA, N_NODES, 128, dflag);
  k_agg<<<1024, 256, 0, stream>>>(bufA, offs, csr, dinv, bufB, N_NODES, nullptr, 1);
  k_agg<<<1024, 256, 0, stream>>>(bufB, offs, csr, dinv, bufA, N_NODES, nullptr, 0);
  k_gemm<8, 4><<<gemmN_grid, 256, 0, stream>>>(bufA, w2cT, bufA, N_NODES, 128);

  // ---- fused predictor (reads bufA in ws; writes pred region of d_out) ----
  k_pred<<<P_PAIRS / 64, 256, 0, stream>>>(bufA, z, peB, ps, pt, tn, wp1T, bp1, wp2T,
                                           bp2, pmask, d_out, dflag);
}

// Round 4
// 844.605 us; speedup vs baseline: 1.6902x; 1.6902x over previous
//
#include <hip/hip_runtime.h>
#include <hip/hip_bf16.h>

#define N_NODES 100000
#define E_EDGES 1600000
#define T_TGT   4096
#define P_PAIRS 131072
#define NCHUNK  98   // ceil(N_NODES/1024)

typedef __bf16 bf16x8 __attribute__((ext_vector_type(8)));
typedef float  f32x4  __attribute__((ext_vector_type(4)));

__device__ __forceinline__ float b2f(unsigned short u) {
  unsigned int x = ((unsigned int)u) << 16;
  return __builtin_bit_cast(float, x);
}
__device__ __forceinline__ unsigned short f2b(float f) {
  unsigned int x = __builtin_bit_cast(unsigned int, f);
  x += 0x7fffu + ((x >> 16) & 1u);
  return (unsigned short)(x >> 16);
}
__device__ __forceinline__ bf16x8 ld8(const unsigned short* p) {
  return *reinterpret_cast<const bf16x8*>(p);
}
__device__ __forceinline__ f32x4 mfma16(bf16x8 a, bf16x8 b, f32x4 c) {
  return __builtin_amdgcn_mfma_f32_16x16x32_bf16(a, b, c, 0, 0, 0);
}
// dual-dtype scalar read: element i of a float tensor that is fp32 or bf16
__device__ __forceinline__ float ldf(const void* p, size_t i, bool f32) {
  return f32 ? ((const float*)p)[i] : b2f(((const unsigned short*)p)[i]);
}
// dual-dtype 8-element A/B fragment load (elem = element offset, 8 contiguous)
__device__ __forceinline__ bf16x8 ld8d(const void* p, size_t elem, bool f32) {
  if (!f32) return ld8((const unsigned short*)p + elem);
  const float* q = (const float*)p + elem;
  union { bf16x8 v; unsigned short s[8]; } u;
#pragma unroll
  for (int j = 0; j < 8; ++j) u.s[j] = f2b(q[j]);
  return u.v;
}

// ---------------- dtype sniff ----------------
__global__ void k_sniff(const unsigned int* __restrict__ x, int* __restrict__ dflag) {
  unsigned int w = x[(size_t)threadIdx.x * 24001];
  int e = (w >> 7) & 0xff;
  if (e < 90 || e > 140) atomicAdd(dflag, 1);
}

// ---------------- graph prep ----------------
__global__ void k_hist(const int* __restrict__ dst, int* __restrict__ cnt) {
  for (int e = blockIdx.x * blockDim.x + threadIdx.x; e < E_EDGES;
       e += gridDim.x * blockDim.x)
    atomicAdd(&cnt[dst[e]], 1);
}

__global__ void k_deginv(const int* __restrict__ cnt, float* __restrict__ dinv) {
  int n = blockIdx.x * blockDim.x + threadIdx.x;
  if (n < N_NODES) dinv[n] = 1.0f / (float)max(cnt[n], 1);
}

__global__ void k_scan_a(const int* __restrict__ cnt, int* __restrict__ part) {
  __shared__ int sd[256];
  int t = threadIdx.x;
  int base = blockIdx.x * 1024 + t * 4;
  int s = 0;
  for (int j = 0; j < 4; ++j) {
    int idx = base + j;
    if (idx < N_NODES) s += cnt[idx];
  }
  sd[t] = s; __syncthreads();
  for (int off = 128; off > 0; off >>= 1) {
    if (t < off) sd[t] += sd[t + off];
    __syncthreads();
  }
  if (t == 0) part[blockIdx.x] = sd[0];
}

__global__ void k_scan_b(int* __restrict__ part, int* __restrict__ offs) {
  int run = 0;
  for (int i = 0; i < NCHUNK; ++i) { int v = part[i]; part[i] = run; run += v; }
  offs[N_NODES] = run;
}

__global__ void k_scan_c(const int* __restrict__ cnt, const int* __restrict__ part,
                         int* __restrict__ offs) {
  __shared__ int sd[256];
  int t = threadIdx.x;
  int base = blockIdx.x * 1024 + t * 4;
  int v[4]; int s = 0;
  for (int j = 0; j < 4; ++j) {
    int idx = base + j;
    v[j] = (idx < N_NODES) ? cnt[idx] : 0;
    s += v[j];
  }
  sd[t] = s; __syncthreads();
  for (int off = 1; off < 256; off <<= 1) {
    int x = (t >= off) ? sd[t - off] : 0;
    __syncthreads();
    sd[t] += x;
    __syncthreads();
  }
  int excl = sd[t] - s + part[blockIdx.x];
  for (int j = 0; j < 4; ++j) {
    int idx = base + j;
    if (idx < N_NODES) { offs[idx] = excl; excl += v[j]; }
  }
}

__global__ void k_fill(const int* __restrict__ src, const int* __restrict__ dst,
                       const int* __restrict__ offs, int* __restrict__ cur,
                       int* __restrict__ csr) {
  for (int e = blockIdx.x * blockDim.x + threadIdx.x; e < E_EDGES;
       e += gridDim.x * blockDim.x) {
    int d = dst[e];
    int p = offs[d] + atomicAdd(&cur[d], 1);
    csr[p] = src[e];
  }
}

// ---------------- small utils (dual-dtype reads) ----------------
__global__ void k_transpose(const void* __restrict__ in,
                            unsigned short* __restrict__ out, int K, int Nc,
                            int Kpad, int total, const int* __restrict__ dflag) {
  bool f32 = *dflag > 128;
  int i = blockIdx.x * blockDim.x + threadIdx.x;
  if (i >= total) return;
  int n = i / Kpad, k = i % Kpad;
  out[i] = (k < K) ? f2b(ldf(in, (size_t)k * Nc + n, f32)) : (unsigned short)0;
}

__global__ void k_pe(const void* __restrict__ pos, const void* __restrict__ wpe,
                     unsigned short* __restrict__ pe, const int* __restrict__ dflag) {
  bool f32 = *dflag > 128;
  int n = blockIdx.x * blockDim.x + threadIdx.x;
  if (n >= N_NODES) return;
  float p[4];
  for (int j = 0; j < 4; ++j) p[j] = ldf(pos, (size_t)n * 4 + j, f32);
  for (int i = 0; i < 4; ++i) {
    float acc = 0.f;
    for (int j = 0; j < 4; ++j) acc += p[j] * ldf(wpe, i * 4 + j, f32);  // pos @ Wpe.T
    pe[(size_t)n * 4 + i] = f2b(acc);
  }
}

// ---------------- aggregation (CSR gather, 4-way edge ILP) ----------------
// Wave = 4 groups x 16 lanes. Group g handles edge j+g; lane li loads 16B
// (8 ch) of the source row -> 4 gathers (dwordx4) in flight per wave.
// Cross-group reduction via shfl_xor(16/32); group 0 stores the row.
__global__ void k_agg(const unsigned short* __restrict__ in,
                      const int* __restrict__ offs, const int* __restrict__ csr,
                      const float* __restrict__ dinv,
                      unsigned short* __restrict__ out, int nrows,
                      const int* __restrict__ map, int relu) {
  const int lane = threadIdx.x & 63;
  const int g = lane >> 4;
  const int li = lane & 15;
  int gw = (blockIdx.x * blockDim.x + threadIdx.x) >> 6;
  int nw = (gridDim.x * blockDim.x) >> 6;
  for (int i = gw; i < nrows; i += nw) {
    int n = map ? map[i] : i;
    int b = offs[n], e = offs[n + 1];
    float a[8] = {0.f, 0.f, 0.f, 0.f, 0.f, 0.f, 0.f, 0.f};
    for (int j = b + g; j < e; j += 4) {
      int s = csr[j];
      const uint4 v =
          *reinterpret_cast<const uint4*>(in + (size_t)s * 128 + li * 8);
      a[0] += b2f((unsigned short)(v.x & 0xffffu));
      a[1] += b2f((unsigned short)(v.x >> 16));
      a[2] += b2f((unsigned short)(v.y & 0xffffu));
      a[3] += b2f((unsigned short)(v.y >> 16));
      a[4] += b2f((unsigned short)(v.z & 0xffffu));
      a[5] += b2f((unsigned short)(v.z >> 16));
      a[6] += b2f((unsigned short)(v.w & 0xffffu));
      a[7] += b2f((unsigned short)(v.w >> 16));
    }
#pragma unroll
    for (int c = 0; c < 8; ++c) {
      a[c] += __shfl_xor(a[c], 16);
      a[c] += __shfl_xor(a[c], 32);
    }
    if (g == 0) {
      float sc = dinv[n];
#pragma unroll
      for (int c = 0; c < 8; ++c) {
        a[c] *= sc;
        if (relu) a[c] = fmaxf(a[c], 0.f);
      }
      uint4 o;
      o.x = (unsigned int)f2b(a[0]) | ((unsigned int)f2b(a[1]) << 16);
      o.y = (unsigned int)f2b(a[2]) | ((unsigned int)f2b(a[3]) << 16);
      o.z = (unsigned int)f2b(a[4]) | ((unsigned int)f2b(a[5]) << 16);
      o.w = (unsigned int)f2b(a[6]) | ((unsigned int)f2b(a[7]) << 16);
      *reinterpret_cast<uint4*>(out + (size_t)i * 128 + li * 8) = o;
    }
  }
}

// ---------------- GEMMs (bf16 MFMA 16x16x32) ----------------
template <int NT, int KS>
__global__ void __launch_bounds__(256) k_gemm_in(const void* __restrict__ A,
                                                 const unsigned short* __restrict__ BT,
                                                 unsigned short* __restrict__ C, int M,
                                                 int ldb,
                                                 const int* __restrict__ dflag) {
  bool f32 = *dflag > 128;
  const int wid = threadIdx.x >> 6;
  const int lane = threadIdx.x & 63;
  const int lr = lane & 15;
  const int q = lane >> 4;
  const int m0 = blockIdx.x * 64 + wid * 16;
  if (m0 >= M) return;
  f32x4 acc[NT];
#pragma unroll
  for (int i = 0; i < NT; ++i) acc[i] = f32x4{0.f, 0.f, 0.f, 0.f};
  const size_t abase = (size_t)(m0 + lr) * (KS * 32) + q * 8;
#pragma unroll
  for (int ks = 0; ks < KS; ++ks) {
    bf16x8 a = ld8d(A, abase + ks * 32, f32);
#pragma unroll
    for (int nt = 0; nt < NT; ++nt) {
      bf16x8 b = ld8(BT + (size_t)(nt * 16 + lr) * ldb + ks * 32 + q * 8);
      acc[nt] = mfma16(a, b, acc[nt]);
    }
  }
#pragma unroll
  for (int nt = 0; nt < NT; ++nt)
#pragma unroll
    for (int r = 0; r < 4; ++r)
      C[(size_t)(m0 + q * 4 + r) * (NT * 16) + nt * 16 + lr] = f2b(acc[nt][r]);
}

// pure-bf16 GEMM (safe in-place C==A: wave reads only its own 16-row slab)
template <int NT, int KS>
__global__ void __launch_bounds__(256) k_gemm(const unsigned short* __restrict__ A,
                                              const unsigned short* __restrict__ BT,
                                              unsigned short* __restrict__ C, int M,
                                              int ldb) {
  const int wid = threadIdx.x >> 6;
  const int lane = threadIdx.x & 63;
  const int lr = lane & 15;
  const int q = lane >> 4;
  const int m0 = blockIdx.x * 64 + wid * 16;
  if (m0 >= M) return;
  f32x4 acc[NT];
#pragma unroll
  for (int i = 0; i < NT; ++i) acc[i] = f32x4{0.f, 0.f, 0.f, 0.f};
  const unsigned short* arow = A + (size_t)(m0 + lr) * (KS * 32) + q * 8;
#pragma unroll
  for (int ks = 0; ks < KS; ++ks) {
    bf16x8 a = ld8(arow + ks * 32);
#pragma unroll
    for (int nt = 0; nt < NT; ++nt) {
      bf16x8 b = ld8(BT + (size_t)(nt * 16 + lr) * ldb + ks * 32 + q * 8);
      acc[nt] = mfma16(a, b, acc[nt]);
    }
  }
#pragma unroll
  for (int nt = 0; nt < NT; ++nt)
#pragma unroll
    for (int r = 0; r < 4; ++r)
      C[(size_t)(m0 + q * 4 + r) * (NT * 16) + nt * 16 + lr] = f2b(acc[nt][r]);
}

// target-embedding GEMM: bf16 A -> dual-dtype store into d_out at elem_off
template <int NT, int KS>
__global__ void __launch_bounds__(256) k_gemm_out(const unsigned short* __restrict__ A,
                                                  const unsigned short* __restrict__ BT,
                                                  void* __restrict__ C, size_t elem_off,
                                                  int M, int ldb,
                                                  const int* __restrict__ dflag) {
  bool f32 = *dflag > 128;
  const int wid = threadIdx.x >> 6;
  const int lane = threadIdx.x & 63;
  const int lr = lane & 15;
  const int q = lane >> 4;
  const int m0 = blockIdx.x * 64 + wid * 16;
  if (m0 >= M) return;
  f32x4 acc[NT];
#pragma unroll
  for (int i = 0; i < NT; ++i) acc[i] = f32x4{0.f, 0.f, 0.f, 0.f};
  const unsigned short* arow = A + (size_t)(m0 + lr) * (KS * 32) + q * 8;
#pragma unroll
  for (int ks = 0; ks < KS; ++ks) {
    bf16x8 a = ld8(arow + ks * 32);
#pragma unroll
    for (int nt = 0; nt < NT; ++nt) {
      bf16x8 b = ld8(BT + (size_t)(nt * 16 + lr) * ldb + ks * 32 + q * 8);
      acc[nt] = mfma16(a, b, acc[nt]);
    }
  }
#pragma unroll
  for (int nt = 0; nt < NT; ++nt)
#pragma unroll
    for (int r = 0; r < 4; ++r) {
      size_t idx = elem_off + (size_t)(m0 + q * 4 + r) * (NT * 16) + nt * 16 + lr;
      if (f32) ((float*)C)[idx] = acc[nt][r];
      else     ((unsigned short*)C)[idx] = f2b(acc[nt][r]);
    }
}

// ---------------- fused predictor ----------------
__global__ void __launch_bounds__(256) k_pred(
    const unsigned short* __restrict__ ctx, const void* __restrict__ z,
    const unsigned short* __restrict__ pe, const int* __restrict__ pair_s,
    const int* __restrict__ pair_t, const int* __restrict__ tn,
    const unsigned short* __restrict__ w1T, const void* __restrict__ b1,
    const unsigned short* __restrict__ w2T, const void* __restrict__ b2,
    const void* __restrict__ pmask, void* __restrict__ out,
    const int* __restrict__ dflag) {
  bool f32 = *dflag > 128;
  __shared__ unsigned short sh[4][16][264];  // +8 pad breaks bank clash
  const int wid = threadIdx.x >> 6;
  const int lane = threadIdx.x & 63;
  const int lr = lane & 15;
  const int q = lane >> 4;
  const int m0 = blockIdx.x * 64 + wid * 16;
  const int row = m0 + lr;
  const int s = pair_s[row];
  const int tno = tn[pair_t[row]];
  const unsigned short* ctxrow = ctx + (size_t)s * 128 + q * 8;

  // ---- layer 1 ----
  f32x4 acc[16];
#pragma unroll
  for (int i = 0; i < 16; ++i) acc[i] = f32x4{0.f, 0.f, 0.f, 0.f};
#pragma unroll
  for (int ks = 0; ks < 7; ++ks) {
    const int kb = ks * 32 + q * 8;
    bf16x8 a;
    if (kb < 128) {
      a = ld8(ctxrow + ks * 32);
    } else if (kb < 192) {
      a = ld8d(z, kb - 128, f32);
    } else if (kb == 192) {
      union { bf16x8 v; unsigned long long d[2]; } u;
      u.d[0] = *reinterpret_cast<const unsigned long long*>(pe + (size_t)s * 4);
      u.d[1] = *reinterpret_cast<const unsigned long long*>(pe + (size_t)tno * 4);
      a = u.v;
    } else {
      union { bf16x8 v; unsigned long long d[2]; } u;
      u.d[0] = 0; u.d[1] = 0;
      a = u.v;
    }
#pragma unroll
    for (int nt = 0; nt < 16; ++nt) {
      bf16x8 b = ld8(w1T + (size_t)(nt * 16 + lr) * 224 + kb);
      acc[nt] = mfma16(a, b, acc[nt]);
    }
  }
#pragma unroll
  for (int nt = 0; nt < 16; ++nt) {
    float bias = ldf(b1, nt * 16 + lr, f32);
#pragma unroll
    for (int r = 0; r < 4; ++r)
      sh[wid][q * 4 + r][nt * 16 + lr] = f2b(fmaxf(acc[nt][r] + bias, 0.f));
  }
  __syncthreads();

  // ---- layer 2 ----
  f32x4 acc2[8];
#pragma unroll
  for (int i = 0; i < 8; ++i) acc2[i] = f32x4{0.f, 0.f, 0.f, 0.f};
  const unsigned short* hrow = &sh[wid][lr][q * 8];
#pragma unroll
  for (int ks = 0; ks < 8; ++ks) {
    bf16x8 a = ld8(hrow + ks * 32);
#pragma unroll
    for (int nt = 0; nt < 8; ++nt) {
      bf16x8 b = ld8(w2T + (size_t)(nt * 16 + lr) * 256 + ks * 32 + q * 8);
      acc2[nt] = mfma16(a, b, acc2[nt]);
    }
  }
#pragma unroll
  for (int nt = 0; nt < 8; ++nt) {
    float bias = ldf(b2, nt * 16 + lr, f32);
#pragma unroll
    for (int r = 0; r < 4; ++r) {
      int rr = m0 + q * 4 + r;
      float mk = ldf(pmask, rr, f32);
      float v = (acc2[nt][r] + bias) * mk;
      size_t idx = (size_t)rr * 128 + nt * 16 + lr;
      if (f32) ((float*)out)[idx] = v;
      else     ((unsigned short*)out)[idx] = f2b(v);
    }
  }
}

extern "C" void kernel_launch(void* const* d_in, const int* in_sizes, int n_in,
                              void* d_out, int out_size, void* d_ws, size_t ws_size,
                              hipStream_t stream) {
  const void* x    = d_in[0];
  const void* mx   = d_in[1];
  const void* pos  = d_in[2];
  const int* esrc  = (const int*)d_in[3];
  const int* edst  = (const int*)d_in[4];
  const int* tn    = (const int*)d_in[5];
  const int* pt    = (const int*)d_in[6];
  const int* ps    = (const int*)d_in[7];
  const void* pmask= d_in[8];
  const void* W1t  = d_in[9];
  const void* W2t  = d_in[10];
  const void* W1c  = d_in[11];
  const void* W2c  = d_in[12];
  const void* Wpe  = d_in[13];
  const void* z    = d_in[14];
  const void* Wp1  = d_in[15];
  const void* bp1  = d_in[16];
  const void* Wp2  = d_in[17];
  const void* bp2  = d_in[18];

  char* w = (char*)d_ws;
  auto carve = [&](size_t bytes) -> void* {
    void* p = (void*)w;
    w += (bytes + 255) & ~(size_t)255;
    return p;
  };
  int*   dflag = (int*)carve(256);
  int*   offs  = (int*)carve((N_NODES + 1) * sizeof(int));
  int*   cur   = (int*)carve(N_NODES * sizeof(int));
  int*   part  = (int*)carve(4096);
  int*   csr   = (int*)carve(E_EDGES * sizeof(int));
  float* dinv  = (float*)carve(N_NODES * sizeof(float));
  unsigned short* bufA  = (unsigned short*)carve((size_t)N_NODES * 128 * 2);
  unsigned short* peB   = (unsigned short*)carve((size_t)N_NODES * 4 * 2);
  unsigned short* gt    = (unsigned short*)carve((size_t)T_TGT * 128 * 2);
  unsigned short* w1tT  = (unsigned short*)carve(128 * 128 * 2);
  unsigned short* w2tT  = (unsigned short*)carve(128 * 128 * 2);
  unsigned short* w1cT  = (unsigned short*)carve(128 * 128 * 2);
  unsigned short* w2cT  = (unsigned short*)carve(128 * 128 * 2);
  unsigned short* wp1T  = (unsigned short*)carve(256 * 224 * 2);
  unsigned short* wp2T  = (unsigned short*)carve(128 * 256 * 2);
  // bufB overlays d_out's pred region (>= 25.6MB in both dtypes; pred rows
  // are written last, so earlier uses are dead by then).
  unsigned short* bufB = (unsigned short*)d_out;

  // ---- dtype sniff ----
  hipMemsetAsync(dflag, 0, sizeof(int), stream);
  k_sniff<<<1, 256, 0, stream>>>((const unsigned int*)x, dflag);

  // ---- graph prep (CSR by dst + degrees) ----
  hipMemsetAsync(cur, 0, N_NODES * sizeof(int), stream);
  k_hist<<<1024, 256, 0, stream>>>(edst, cur);
  k_deginv<<<(N_NODES + 255) / 256, 256, 0, stream>>>(cur, dinv);
  k_scan_a<<<NCHUNK, 256, 0, stream>>>(cur, part);
  k_scan_b<<<1, 1, 0, stream>>>(part, offs);
  k_scan_c<<<NCHUNK, 256, 0, stream>>>(cur, part, offs);
  hipMemsetAsync(cur, 0, N_NODES * sizeof(int), stream);
  k_fill<<<1024, 256, 0, stream>>>(esrc, edst, offs, cur, csr);

  // ---- weight transposes (B^T layouts, dual-dtype reads) ----
  k_transpose<<<64, 256, 0, stream>>>(W1t, w1tT, 128, 128, 128, 128 * 128, dflag);
  k_transpose<<<64, 256, 0, stream>>>(W2t, w2tT, 128, 128, 128, 128 * 128, dflag);
  k_transpose<<<64, 256, 0, stream>>>(W1c, w1cT, 128, 128, 128, 128 * 128, dflag);
  k_transpose<<<64, 256, 0, stream>>>(W2c, w2cT, 128, 128, 128, 128 * 128, dflag);
  k_transpose<<<(256 * 224 + 255) / 256, 256, 0, stream>>>(Wp1, wp1T, 200, 256, 224,
                                                           256 * 224, dflag);
  k_transpose<<<128, 256, 0, stream>>>(Wp2, wp2T, 256, 128, 256, 128 * 256, dflag);

  k_pe<<<(N_NODES + 255) / 256, 256, 0, stream>>>(pos, Wpe, peB, dflag);

  const int gemmN_grid = (N_NODES + 63) / 64;  // 1563
  const int aggN_grid = 4096;   // 16384 waves: full occupancy + grid-stride
  const int aggT_grid = 1024;   // 4096 rows, 1 row/wave

  // ---- target GCN: emb = (agg(relu(agg(x@W1t)))[targets]) @ W2t ----
  k_gemm_in<8, 4><<<gemmN_grid, 256, 0, stream>>>(x, w1tT, bufA, N_NODES, 128, dflag);
  k_agg<<<aggN_grid, 256, 0, stream>>>(bufA, offs, csr, dinv, bufB, N_NODES, nullptr, 1);
  k_agg<<<aggT_grid, 256, 0, stream>>>(bufB, offs, csr, dinv, gt, T_TGT, tn, 0);
  k_gemm_out<8, 4><<<T_TGT / 64, 256, 0, stream>>>(gt, w2tT, d_out,
                                                   (size_t)P_PAIRS * 128, T_TGT, 128,
                                                   dflag);

  // ---- context GCN: ctx = agg(relu(agg(mx@W1c))) @ W2c ----
  k_gemm_in<8, 4><<<gemmN_grid, 256, 0, stream>>>(mx, w1cT, bufA, N_NODES, 128, dflag);
  k_agg<<<aggN_grid, 256, 0, stream>>>(bufA, offs, csr, dinv, bufB, N_NODES, nullptr, 1);
  k_agg<<<aggN_grid, 256, 0, stream>>>(bufB, offs, csr, dinv, bufA, N_NODES, nullptr, 0);
  k_gemm<8, 4><<<gemmN_grid, 256, 0, stream>>>(bufA, w2cT, bufA, N_NODES, 128);

  // ---- fused predictor (reads bufA in ws; writes pred region of d_out) ----
  k_pred<<<P_PAIRS / 64, 256, 0, stream>>>(bufA, z, peB, ps, pt, tn, wp1T, bp1, wp2T,
                                           bp2, pmask, d_out, dflag);
}

// Round 5
// 746.108 us; speedup vs baseline: 1.9133x; 1.1320x over previous
//
#include <hip/hip_runtime.h>
#include <hip/hip_bf16.h>

#define N_NODES 100000
#define E_EDGES 1600000
#define T_TGT   4096
#define P_PAIRS 131072
#define NCHUNK  98   // ceil(N_NODES/1024)

typedef __bf16 bf16x8 __attribute__((ext_vector_type(8)));
typedef float  f32x4  __attribute__((ext_vector_type(4)));

__device__ __forceinline__ float b2f(unsigned short u) {
  unsigned int x = ((unsigned int)u) << 16;
  return __builtin_bit_cast(float, x);
}
__device__ __forceinline__ unsigned short f2b(float f) {
  unsigned int x = __builtin_bit_cast(unsigned int, f);
  x += 0x7fffu + ((x >> 16) & 1u);
  return (unsigned short)(x >> 16);
}
__device__ __forceinline__ bf16x8 ld8(const unsigned short* p) {
  return *reinterpret_cast<const bf16x8*>(p);
}
__device__ __forceinline__ f32x4 mfma16(bf16x8 a, bf16x8 b, f32x4 c) {
  return __builtin_amdgcn_mfma_f32_16x16x32_bf16(a, b, c, 0, 0, 0);
}
// dual-dtype scalar read: element i of a float tensor that is fp32 or bf16
__device__ __forceinline__ float ldf(const void* p, size_t i, bool f32) {
  return f32 ? ((const float*)p)[i] : b2f(((const unsigned short*)p)[i]);
}
// dual-dtype 8-element A/B fragment load (elem = element offset, 8 contiguous)
__device__ __forceinline__ bf16x8 ld8d(const void* p, size_t elem, bool f32) {
  if (!f32) return ld8((const unsigned short*)p + elem);
  const float* q = (const float*)p + elem;
  union { bf16x8 v; unsigned short s[8]; } u;
#pragma unroll
  for (int j = 0; j < 8; ++j) u.s[j] = f2b(q[j]);
  return u.v;
}

// ---------------- dtype sniff ----------------
__global__ void k_sniff(const unsigned int* __restrict__ x, int* __restrict__ dflag) {
  unsigned int w = x[(size_t)threadIdx.x * 24001];
  int e = (w >> 7) & 0xff;
  if (e < 90 || e > 140) atomicAdd(dflag, 1);
}

// ---------------- graph prep ----------------
__global__ void k_hist(const int* __restrict__ dst, int* __restrict__ cnt) {
  for (int e = blockIdx.x * blockDim.x + threadIdx.x; e < E_EDGES;
       e += gridDim.x * blockDim.x)
    atomicAdd(&cnt[dst[e]], 1);
}

__global__ void k_deginv(const int* __restrict__ cnt, float* __restrict__ dinv) {
  int n = blockIdx.x * blockDim.x + threadIdx.x;
  if (n < N_NODES) dinv[n] = 1.0f / (float)max(cnt[n], 1);
}

__global__ void k_scan_a(const int* __restrict__ cnt, int* __restrict__ part) {
  __shared__ int sd[256];
  int t = threadIdx.x;
  int base = blockIdx.x * 1024 + t * 4;
  int s = 0;
  for (int j = 0; j < 4; ++j) {
    int idx = base + j;
    if (idx < N_NODES) s += cnt[idx];
  }
  sd[t] = s; __syncthreads();
  for (int off = 128; off > 0; off >>= 1) {
    if (t < off) sd[t] += sd[t + off];
    __syncthreads();
  }
  if (t == 0) part[blockIdx.x] = sd[0];
}

__global__ void k_scan_b(int* __restrict__ part, int* __restrict__ offs) {
  int run = 0;
  for (int i = 0; i < NCHUNK; ++i) { int v = part[i]; part[i] = run; run += v; }
  offs[N_NODES] = run;
}

__global__ void k_scan_c(const int* __restrict__ cnt, const int* __restrict__ part,
                         int* __restrict__ offs) {
  __shared__ int sd[256];
  int t = threadIdx.x;
  int base = blockIdx.x * 1024 + t * 4;
  int v[4]; int s = 0;
  for (int j = 0; j < 4; ++j) {
    int idx = base + j;
    v[j] = (idx < N_NODES) ? cnt[idx] : 0;
    s += v[j];
  }
  sd[t] = s; __syncthreads();
  for (int off = 1; off < 256; off <<= 1) {
    int x = (t >= off) ? sd[t - off] : 0;
    __syncthreads();
    sd[t] += x;
    __syncthreads();
  }
  int excl = sd[t] - s + part[blockIdx.x];
  for (int j = 0; j < 4; ++j) {
    int idx = base + j;
    if (idx < N_NODES) { offs[idx] = excl; excl += v[j]; }
  }
}

__global__ void k_fill(const int* __restrict__ src, const int* __restrict__ dst,
                       const int* __restrict__ offs, int* __restrict__ cur,
                       int* __restrict__ csr) {
  for (int e = blockIdx.x * blockDim.x + threadIdx.x; e < E_EDGES;
       e += gridDim.x * blockDim.x) {
    int d = dst[e];
    int p = offs[d] + atomicAdd(&cur[d], 1);
    csr[p] = src[e];
  }
}

// ---------------- small utils (dual-dtype reads) ----------------
__global__ void k_transpose(const void* __restrict__ in,
                            unsigned short* __restrict__ out, int K, int Nc,
                            int Kpad, int total, const int* __restrict__ dflag) {
  bool f32 = *dflag > 128;
  int i = blockIdx.x * blockDim.x + threadIdx.x;
  if (i >= total) return;
  int n = i / Kpad, k = i % Kpad;
  out[i] = (k < K) ? f2b(ldf(in, (size_t)k * Nc + n, f32)) : (unsigned short)0;
}

__global__ void k_pe(const void* __restrict__ pos, const void* __restrict__ wpe,
                     unsigned short* __restrict__ pe, const int* __restrict__ dflag) {
  bool f32 = *dflag > 128;
  int n = blockIdx.x * blockDim.x + threadIdx.x;
  if (n >= N_NODES) return;
  float p[4];
  for (int j = 0; j < 4; ++j) p[j] = ldf(pos, (size_t)n * 4 + j, f32);
  for (int i = 0; i < 4; ++i) {
    float acc = 0.f;
    for (int j = 0; j < 4; ++j) acc += p[j] * ldf(wpe, i * 4 + j, f32);  // pos @ Wpe.T
    pe[(size_t)n * 4 + i] = f2b(acc);
  }
}

// ---------------- aggregation (CSR gather, 4-way edge ILP) ----------------
__global__ void k_agg(const unsigned short* __restrict__ in,
                      const int* __restrict__ offs, const int* __restrict__ csr,
                      const float* __restrict__ dinv,
                      unsigned short* __restrict__ out, int nrows,
                      const int* __restrict__ map, int relu) {
  const int lane = threadIdx.x & 63;
  const int g = lane >> 4;
  const int li = lane & 15;
  int gw = (blockIdx.x * blockDim.x + threadIdx.x) >> 6;
  int nw = (gridDim.x * blockDim.x) >> 6;
  for (int i = gw; i < nrows; i += nw) {
    int n = map ? map[i] : i;
    int b = offs[n], e = offs[n + 1];
    float a[8] = {0.f, 0.f, 0.f, 0.f, 0.f, 0.f, 0.f, 0.f};
    for (int j = b + g; j < e; j += 4) {
      int s = csr[j];
      const uint4 v =
          *reinterpret_cast<const uint4*>(in + (size_t)s * 128 + li * 8);
      a[0] += b2f((unsigned short)(v.x & 0xffffu));
      a[1] += b2f((unsigned short)(v.x >> 16));
      a[2] += b2f((unsigned short)(v.y & 0xffffu));
      a[3] += b2f((unsigned short)(v.y >> 16));
      a[4] += b2f((unsigned short)(v.z & 0xffffu));
      a[5] += b2f((unsigned short)(v.z >> 16));
      a[6] += b2f((unsigned short)(v.w & 0xffffu));
      a[7] += b2f((unsigned short)(v.w >> 16));
    }
#pragma unroll
    for (int c = 0; c < 8; ++c) {
      a[c] += __shfl_xor(a[c], 16);
      a[c] += __shfl_xor(a[c], 32);
    }
    if (g == 0) {
      float sc = dinv[n];
#pragma unroll
      for (int c = 0; c < 8; ++c) {
        a[c] *= sc;
        if (relu) a[c] = fmaxf(a[c], 0.f);
      }
      uint4 o;
      o.x = (unsigned int)f2b(a[0]) | ((unsigned int)f2b(a[1]) << 16);
      o.y = (unsigned int)f2b(a[2]) | ((unsigned int)f2b(a[3]) << 16);
      o.z = (unsigned int)f2b(a[4]) | ((unsigned int)f2b(a[5]) << 16);
      o.w = (unsigned int)f2b(a[6]) | ((unsigned int)f2b(a[7]) << 16);
      *reinterpret_cast<uint4*>(out + (size_t)i * 128 + li * 8) = o;
    }
  }
}

// ---------------- GEMMs (bf16 MFMA 16x16x32) ----------------
template <int NT, int KS>
__global__ void __launch_bounds__(256) k_gemm_in(const void* __restrict__ A,
                                                 const unsigned short* __restrict__ BT,
                                                 unsigned short* __restrict__ C, int M,
                                                 int ldb,
                                                 const int* __restrict__ dflag) {
  bool f32 = *dflag > 128;
  const int wid = threadIdx.x >> 6;
  const int lane = threadIdx.x & 63;
  const int lr = lane & 15;
  const int q = lane >> 4;
  const int m0 = blockIdx.x * 64 + wid * 16;
  if (m0 >= M) return;
  f32x4 acc[NT];
#pragma unroll
  for (int i = 0; i < NT; ++i) acc[i] = f32x4{0.f, 0.f, 0.f, 0.f};
  const size_t abase = (size_t)(m0 + lr) * (KS * 32) + q * 8;
#pragma unroll
  for (int ks = 0; ks < KS; ++ks) {
    bf16x8 a = ld8d(A, abase + ks * 32, f32);
#pragma unroll
    for (int nt = 0; nt < NT; ++nt) {
      bf16x8 b = ld8(BT + (size_t)(nt * 16 + lr) * ldb + ks * 32 + q * 8);
      acc[nt] = mfma16(a, b, acc[nt]);
    }
  }
#pragma unroll
  for (int nt = 0; nt < NT; ++nt)
#pragma unroll
    for (int r = 0; r < 4; ++r)
      C[(size_t)(m0 + q * 4 + r) * (NT * 16) + nt * 16 + lr] = f2b(acc[nt][r]);
}

// pure-bf16 GEMM (safe in-place C==A: wave reads only its own 16-row slab)
template <int NT, int KS>
__global__ void __launch_bounds__(256) k_gemm(const unsigned short* __restrict__ A,
                                              const unsigned short* __restrict__ BT,
                                              unsigned short* __restrict__ C, int M,
                                              int ldb) {
  const int wid = threadIdx.x >> 6;
  const int lane = threadIdx.x & 63;
  const int lr = lane & 15;
  const int q = lane >> 4;
  const int m0 = blockIdx.x * 64 + wid * 16;
  if (m0 >= M) return;
  f32x4 acc[NT];
#pragma unroll
  for (int i = 0; i < NT; ++i) acc[i] = f32x4{0.f, 0.f, 0.f, 0.f};
  const unsigned short* arow = A + (size_t)(m0 + lr) * (KS * 32) + q * 8;
#pragma unroll
  for (int ks = 0; ks < KS; ++ks) {
    bf16x8 a = ld8(arow + ks * 32);
#pragma unroll
    for (int nt = 0; nt < NT; ++nt) {
      bf16x8 b = ld8(BT + (size_t)(nt * 16 + lr) * ldb + ks * 32 + q * 8);
      acc[nt] = mfma16(a, b, acc[nt]);
    }
  }
#pragma unroll
  for (int nt = 0; nt < NT; ++nt)
#pragma unroll
    for (int r = 0; r < 4; ++r)
      C[(size_t)(m0 + q * 4 + r) * (NT * 16) + nt * 16 + lr] = f2b(acc[nt][r]);
}

// target-embedding GEMM: bf16 A -> dual-dtype store into d_out at elem_off
template <int NT, int KS>
__global__ void __launch_bounds__(256) k_gemm_out(const unsigned short* __restrict__ A,
                                                  const unsigned short* __restrict__ BT,
                                                  void* __restrict__ C, size_t elem_off,
                                                  int M, int ldb,
                                                  const int* __restrict__ dflag) {
  bool f32 = *dflag > 128;
  const int wid = threadIdx.x >> 6;
  const int lane = threadIdx.x & 63;
  const int lr = lane & 15;
  const int q = lane >> 4;
  const int m0 = blockIdx.x * 64 + wid * 16;
  if (m0 >= M) return;
  f32x4 acc[NT];
#pragma unroll
  for (int i = 0; i < NT; ++i) acc[i] = f32x4{0.f, 0.f, 0.f, 0.f};
  const unsigned short* arow = A + (size_t)(m0 + lr) * (KS * 32) + q * 8;
#pragma unroll
  for (int ks = 0; ks < KS; ++ks) {
    bf16x8 a = ld8(arow + ks * 32);
#pragma unroll
    for (int nt = 0; nt < NT; ++nt) {
      bf16x8 b = ld8(BT + (size_t)(nt * 16 + lr) * ldb + ks * 32 + q * 8);
      acc[nt] = mfma16(a, b, acc[nt]);
    }
  }
#pragma unroll
  for (int nt = 0; nt < NT; ++nt)
#pragma unroll
    for (int r = 0; r < 4; ++r) {
      size_t idx = elem_off + (size_t)(m0 + q * 4 + r) * (NT * 16) + nt * 16 + lr;
      if (f32) ((float*)C)[idx] = acc[nt][r];
      else     ((unsigned short*)C)[idx] = f2b(acc[nt][r]);
    }
}

// ---------------- fused predictor, LDS-staged weights ----------------
// Phase A: w1T staged in two 128-row halves into LDS (rows padded 224->232
// shorts: stride 116 dw = 20 mod 32 -> 2-way conflicts only, free).
// Phase B: hid tile -> shH (C->A layout transform), w2T staged in four
// 32-row quarters (rows padded 256->264: 4 mod 32 -> 2-way, free).
// All B-fragment reads become ds_read_b128 instead of L2 round-trips.
__global__ void __launch_bounds__(256) k_pred(
    const unsigned short* __restrict__ ctx, const void* __restrict__ z,
    const unsigned short* __restrict__ pe, const int* __restrict__ pair_s,
    const int* __restrict__ pair_t, const int* __restrict__ tn,
    const unsigned short* __restrict__ w1T, const void* __restrict__ b1,
    const unsigned short* __restrict__ w2T, const void* __restrict__ b2,
    const void* __restrict__ pmask, void* __restrict__ out,
    const int* __restrict__ dflag) {
  bool f32 = *dflag > 128;
  __shared__ __align__(16) char smem[59392];        // max(w1 half, shH+w2 qtr)
  unsigned short* w1L = (unsigned short*)smem;      // [128][232] = 59392 B
  unsigned short* shH = (unsigned short*)smem;      // [4][16][264] = 33792 B
  unsigned short* w2L = (unsigned short*)(smem + 33792);  // [32][264] = 16896 B

  const int tid = threadIdx.x;
  const int wid = tid >> 6;
  const int lane = tid & 63;
  const int lr = lane & 15;
  const int q = lane >> 4;
  const int m0 = blockIdx.x * 64 + wid * 16;
  const int row = m0 + lr;
  const int s = pair_s[row];
  const int tno = tn[pair_t[row]];
  const unsigned short* ctxrow = ctx + (size_t)s * 128 + q * 8;

  // ---- build feat A-fragments once (regs) ----
  bf16x8 af[7];
#pragma unroll
  for (int ks = 0; ks < 7; ++ks) {
    const int kb = ks * 32 + q * 8;
    if (kb < 128) {
      af[ks] = ld8(ctxrow + ks * 32);
    } else if (kb < 192) {
      af[ks] = ld8d(z, kb - 128, f32);
    } else if (kb == 192) {
      union { bf16x8 v; unsigned long long d[2]; } u;
      u.d[0] = *reinterpret_cast<const unsigned long long*>(pe + (size_t)s * 4);
      u.d[1] = *reinterpret_cast<const unsigned long long*>(pe + (size_t)tno * 4);
      af[ks] = u.v;
    } else {
      union { bf16x8 v; unsigned long long d[2]; } u;
      u.d[0] = 0; u.d[1] = 0;
      af[ks] = u.v;
    }
  }

  // ---- layer 1: two staged halves of w1 ----
  f32x4 acc[16];
#pragma unroll
  for (int i = 0; i < 16; ++i) acc[i] = f32x4{0.f, 0.f, 0.f, 0.f};
  for (int h = 0; h < 2; ++h) {
#pragma unroll
    for (int it = 0; it < 14; ++it) {           // 3584 uint4 / 256 thr
      int idx = it * 256 + tid;
      int r = idx / 28, c8 = idx % 28;          // 28 uint4 per 224-short row
      *reinterpret_cast<uint4*>(w1L + r * 232 + c8 * 8) =
          *reinterpret_cast<const uint4*>(w1T + (size_t)(h * 128 + r) * 224 + c8 * 8);
    }
    __syncthreads();
#pragma unroll
    for (int ks = 0; ks < 7; ++ks)
#pragma unroll
      for (int nt = 0; nt < 8; ++nt) {
        bf16x8 b = ld8(w1L + (nt * 16 + lr) * 232 + ks * 32 + q * 8);
        acc[h * 8 + nt] = mfma16(af[ks], b, acc[h * 8 + nt]);
      }
    __syncthreads();
  }

  // ---- bias+relu -> shH (w1L dead), stage w2 quarter 0 ----
#pragma unroll
  for (int nt = 0; nt < 16; ++nt) {
    float bias = ldf(b1, nt * 16 + lr, f32);
#pragma unroll
    for (int r = 0; r < 4; ++r)
      shH[(wid * 16 + q * 4 + r) * 264 + nt * 16 + lr] =
          f2b(fmaxf(acc[nt][r] + bias, 0.f));
  }
#pragma unroll
  for (int it = 0; it < 4; ++it) {              // 1024 uint4 / 256 thr
    int idx = it * 256 + tid;
    int r = idx >> 5, c8 = idx & 31;            // 32 uint4 per 256-short row
    *reinterpret_cast<uint4*>(w2L + r * 264 + c8 * 8) =
        *reinterpret_cast<const uint4*>(w2T + (size_t)r * 256 + c8 * 8);
  }
  __syncthreads();

  // ---- hid A-fragments once (regs) ----
  bf16x8 af2[8];
  const unsigned short* hrow = shH + (wid * 16 + lr) * 264 + q * 8;
#pragma unroll
  for (int ks = 0; ks < 8; ++ks) af2[ks] = ld8(hrow + ks * 32);

  // ---- layer 2: four staged quarters of w2 ----
  f32x4 acc2[8];
#pragma unroll
  for (int i = 0; i < 8; ++i) acc2[i] = f32x4{0.f, 0.f, 0.f, 0.f};
  for (int ph = 0; ph < 4; ++ph) {
    if (ph) {
      __syncthreads();                          // prior compute done
#pragma unroll
      for (int it = 0; it < 4; ++it) {
        int idx = it * 256 + tid;
        int r = idx >> 5, c8 = idx & 31;
        *reinterpret_cast<uint4*>(w2L + r * 264 + c8 * 8) =
            *reinterpret_cast<const uint4*>(w2T + (size_t)(ph * 32 + r) * 256 + c8 * 8);
      }
      __syncthreads();
    }
#pragma unroll
    for (int nt2 = 0; nt2 < 2; ++nt2)
#pragma unroll
      for (int ks = 0; ks < 8; ++ks) {
        bf16x8 b = ld8(w2L + (nt2 * 16 + lr) * 264 + ks * 32 + q * 8);
        acc2[ph * 2 + nt2] = mfma16(af2[ks], b, acc2[ph * 2 + nt2]);
      }
  }

  // ---- epilogue ----
#pragma unroll
  for (int nt = 0; nt < 8; ++nt) {
    float bias = ldf(b2, nt * 16 + lr, f32);
#pragma unroll
    for (int r = 0; r < 4; ++r) {
      int rr = m0 + q * 4 + r;
      float mk = ldf(pmask, rr, f32);
      float v = (acc2[nt][r] + bias) * mk;
      size_t idx = (size_t)rr * 128 + nt * 16 + lr;
      if (f32) ((float*)out)[idx] = v;
      else     ((unsigned short*)out)[idx] = f2b(v);
    }
  }
}

extern "C" void kernel_launch(void* const* d_in, const int* in_sizes, int n_in,
                              void* d_out, int out_size, void* d_ws, size_t ws_size,
                              hipStream_t stream) {
  const void* x    = d_in[0];
  const void* mx   = d_in[1];
  const void* pos  = d_in[2];
  const int* esrc  = (const int*)d_in[3];
  const int* edst  = (const int*)d_in[4];
  const int* tn    = (const int*)d_in[5];
  const int* pt    = (const int*)d_in[6];
  const int* ps    = (const int*)d_in[7];
  const void* pmask= d_in[8];
  const void* W1t  = d_in[9];
  const void* W2t  = d_in[10];
  const void* W1c  = d_in[11];
  const void* W2c  = d_in[12];
  const void* Wpe  = d_in[13];
  const void* z    = d_in[14];
  const void* Wp1  = d_in[15];
  const void* bp1  = d_in[16];
  const void* Wp2  = d_in[17];
  const void* bp2  = d_in[18];

  char* w = (char*)d_ws;
  auto carve = [&](size_t bytes) -> void* {
    void* p = (void*)w;
    w += (bytes + 255) & ~(size_t)255;
    return p;
  };
  int*   dflag = (int*)carve(256);
  int*   offs  = (int*)carve((N_NODES + 1) * sizeof(int));
  int*   cur   = (int*)carve(N_NODES * sizeof(int));
  int*   part  = (int*)carve(4096);
  int*   csr   = (int*)carve(E_EDGES * sizeof(int));
  float* dinv  = (float*)carve(N_NODES * sizeof(float));
  unsigned short* bufA  = (unsigned short*)carve((size_t)N_NODES * 128 * 2);
  unsigned short* peB   = (unsigned short*)carve((size_t)N_NODES * 4 * 2);
  unsigned short* gt    = (unsigned short*)carve((size_t)T_TGT * 128 * 2);
  unsigned short* w1tT  = (unsigned short*)carve(128 * 128 * 2);
  unsigned short* w2tT  = (unsigned short*)carve(128 * 128 * 2);
  unsigned short* w1cT  = (unsigned short*)carve(128 * 128 * 2);
  unsigned short* w2cT  = (unsigned short*)carve(128 * 128 * 2);
  unsigned short* wp1T  = (unsigned short*)carve(256 * 224 * 2);
  unsigned short* wp2T  = (unsigned short*)carve(128 * 256 * 2);
  // bufB overlays d_out's pred region (>= 25.6MB in both dtypes; pred rows
  // are written last, so earlier uses are dead by then).
  unsigned short* bufB = (unsigned short*)d_out;

  // ---- dtype sniff ----
  hipMemsetAsync(dflag, 0, sizeof(int), stream);
  k_sniff<<<1, 256, 0, stream>>>((const unsigned int*)x, dflag);

  // ---- graph prep (CSR by dst + degrees) ----
  hipMemsetAsync(cur, 0, N_NODES * sizeof(int), stream);
  k_hist<<<1024, 256, 0, stream>>>(edst, cur);
  k_deginv<<<(N_NODES + 255) / 256, 256, 0, stream>>>(cur, dinv);
  k_scan_a<<<NCHUNK, 256, 0, stream>>>(cur, part);
  k_scan_b<<<1, 1, 0, stream>>>(part, offs);
  k_scan_c<<<NCHUNK, 256, 0, stream>>>(cur, part, offs);
  hipMemsetAsync(cur, 0, N_NODES * sizeof(int), stream);
  k_fill<<<1024, 256, 0, stream>>>(esrc, edst, offs, cur, csr);

  // ---- weight transposes (B^T layouts, dual-dtype reads) ----
  k_transpose<<<64, 256, 0, stream>>>(W1t, w1tT, 128, 128, 128, 128 * 128, dflag);
  k_transpose<<<64, 256, 0, stream>>>(W2t, w2tT, 128, 128, 128, 128 * 128, dflag);
  k_transpose<<<64, 256, 0, stream>>>(W1c, w1cT, 128, 128, 128, 128 * 128, dflag);
  k_transpose<<<64, 256, 0, stream>>>(W2c, w2cT, 128, 128, 128, 128 * 128, dflag);
  k_transpose<<<(256 * 224 + 255) / 256, 256, 0, stream>>>(Wp1, wp1T, 200, 256, 224,
                                                           256 * 224, dflag);
  k_transpose<<<128, 256, 0, stream>>>(Wp2, wp2T, 256, 128, 256, 128 * 256, dflag);

  k_pe<<<(N_NODES + 255) / 256, 256, 0, stream>>>(pos, Wpe, peB, dflag);

  const int gemmN_grid = (N_NODES + 63) / 64;  // 1563
  const int aggN_grid = 4096;   // 16384 waves: full occupancy + grid-stride
  const int aggT_grid = 1024;   // 4096 rows, 1 row/wave

  // ---- target GCN: emb = (agg(relu(agg(x@W1t)))[targets]) @ W2t ----
  k_gemm_in<8, 4><<<gemmN_grid, 256, 0, stream>>>(x, w1tT, bufA, N_NODES, 128, dflag);
  k_agg<<<aggN_grid, 256, 0, stream>>>(bufA, offs, csr, dinv, bufB, N_NODES, nullptr, 1);
  k_agg<<<aggT_grid, 256, 0, stream>>>(bufB, offs, csr, dinv, gt, T_TGT, tn, 0);
  k_gemm_out<8, 4><<<T_TGT / 64, 256, 0, stream>>>(gt, w2tT, d_out,
                                                   (size_t)P_PAIRS * 128, T_TGT, 128,
                                                   dflag);

  // ---- context GCN: ctx = agg(relu(agg(mx@W1c))) @ W2c ----
  k_gemm_in<8, 4><<<gemmN_grid, 256, 0, stream>>>(mx, w1cT, bufA, N_NODES, 128, dflag);
  k_agg<<<aggN_grid, 256, 0, stream>>>(bufA, offs, csr, dinv, bufB, N_NODES, nullptr, 1);
  k_agg<<<aggN_grid, 256, 0, stream>>>(bufB, offs, csr, dinv, bufA, N_NODES, nullptr, 0);
  k_gemm<8, 4><<<gemmN_grid, 256, 0, stream>>>(bufA, w2cT, bufA, N_NODES, 128);

  // ---- fused predictor (reads bufA in ws; writes pred region of d_out) ----
  k_pred<<<P_PAIRS / 64, 256, 0, stream>>>(bufA, z, peB, ps, pt, tn, wp1T, bp1, wp2T,
                                           bp2, pmask, d_out, dflag);
}